// Round 1
// baseline (478.547 us; speedup 1.0000x reference)
//
#include <hip/hip_runtime.h>
#include <math.h>

#define N_NODES 20000
#define E_EDGES 320000
#define IN_CH   300
#define HID     100
#define R_REL   50
#define NB      8
#define CLS     3
#define NQ      64
#define OUTW    800   // NB * HID
#define ZW      128   // Z row stride (ushorts): 256-B rows, batched-4 writes
#define KP1     320
#define KP2     128
#define SCAN_BLKS ((N_NODES + 255) / 256)   // 79

typedef unsigned short ushort_t;
typedef __attribute__((ext_vector_type(8))) short     short8;
typedef __attribute__((ext_vector_type(8))) unsigned short ushort8;
typedef __attribute__((ext_vector_type(4))) float     f32x4;
typedef __attribute__((ext_vector_type(2))) float     f32x2;

__device__ __forceinline__ ushort_t f2bf_rne(float f) {   // round-nearest-even
    unsigned u = __float_as_uint(f);
    unsigned r = (u + 0x7fffu + ((u >> 16) & 1u)) >> 16;
    return (ushort_t)r;
}
__device__ __forceinline__ float bf2f(ushort_t u) {
    return __uint_as_float((unsigned)u << 16);
}

// ============================ CSR build =================================
__global__ __launch_bounds__(256) void zero_deg2(int* __restrict__ dd,
                                                 int* __restrict__ ds) {
    int i = blockIdx.x * 256 + threadIdx.x;
    if (i < N_NODES) { dd[i] = 0; ds[i] = 0; }
}

__global__ __launch_bounds__(256) void hist2_kernel(
        const int* __restrict__ ei, int* __restrict__ dd,
        int* __restrict__ ds) {
    int e = blockIdx.x * 256 + threadIdx.x;
    if (e < E_EDGES) {
        atomicAdd(&dd[ei[E_EDGES + e]], 1);
        atomicAdd(&ds[ei[e]], 1);
    }
}

// dual-set scans: blockIdx selects (deg_d...) or (deg_s...) set
__global__ __launch_bounds__(256) void scan1_both(
        const int* __restrict__ deg_d, int* __restrict__ rp_d, int* __restrict__ bsum_d,
        const int* __restrict__ deg_s, int* __restrict__ rp_s, int* __restrict__ bsum_s) {
    int set = blockIdx.x / SCAN_BLKS, blk = blockIdx.x % SCAN_BLKS;
    const int* deg = set ? deg_s : deg_d;
    int* rowptr    = set ? rp_s  : rp_d;
    int* bsum      = set ? bsum_s : bsum_d;
    __shared__ int s[256];
    int tid = threadIdx.x;
    int idx = blk * 256 + tid;
    int v = (idx < N_NODES) ? deg[idx] : 0;
    s[tid] = v; __syncthreads();
    #pragma unroll
    for (int off = 1; off < 256; off <<= 1) {
        int t = (tid >= off) ? s[tid - off] : 0;
        __syncthreads();
        s[tid] += t;
        __syncthreads();
    }
    if (idx < N_NODES) rowptr[idx] = s[tid] - v;   // exclusive
    if (tid == 255) bsum[blk] = s[255];
}

__global__ __launch_bounds__(128) void scan2_both(
        int* __restrict__ bsum_d, int* __restrict__ rp_d,
        int* __restrict__ bsum_s, int* __restrict__ rp_s) {
    int* bsum   = blockIdx.x ? bsum_s : bsum_d;
    int* rowptr = blockIdx.x ? rp_s   : rp_d;
    __shared__ int s[128];
    int tid = threadIdx.x;
    int v = (tid < SCAN_BLKS) ? bsum[tid] : 0;
    s[tid] = v; __syncthreads();
    #pragma unroll
    for (int off = 1; off < 128; off <<= 1) {
        int t = (tid >= off) ? s[tid - off] : 0;
        __syncthreads();
        s[tid] += t;
        __syncthreads();
    }
    if (tid < SCAN_BLKS) bsum[tid] = s[tid] - v;   // exclusive
    if (tid == 0) rowptr[N_NODES] = E_EDGES;
}

__global__ __launch_bounds__(256) void scan3_both(
        int* __restrict__ rp_d, const int* __restrict__ bsum_d, int* __restrict__ cur_d,
        int* __restrict__ rp_s, const int* __restrict__ bsum_s, int* __restrict__ cur_s) {
    int set = blockIdx.x / SCAN_BLKS, blk = blockIdx.x % SCAN_BLKS;
    int* rowptr      = set ? rp_s   : rp_d;
    const int* bsum  = set ? bsum_s : bsum_d;
    int* cursor      = set ? cur_s  : cur_d;
    int idx = blk * 256 + threadIdx.x;
    if (idx < N_NODES) {
        int v = rowptr[idx] + bsum[blk];
        rowptr[idx] = v;
        cursor[idx] = v;
    }
}

// fused scatter: dst-CSR key (src,rel), src-CSR key (rel), and zidx map
__global__ __launch_bounds__(256) void scatter_both(
        const int* __restrict__ ei, const int* __restrict__ et,
        int* __restrict__ cur_d, int* __restrict__ cur_s,
        int* __restrict__ skey, int* __restrict__ skey_s,
        int* __restrict__ zidx) {
    int e = blockIdx.x * 256 + threadIdx.x;
    if (e >= E_EDGES) return;
    int s = ei[e], d = ei[E_EDGES + e], rt = et[e];
    int p = atomicAdd(&cur_d[d], 1);
    skey[p] = (s << 6) | rt;                 // dst-order: (src, rel)
    int qp = atomicAdd(&cur_s[s], 1);
    skey_s[qp] = rt;                         // src-order: rel only
    zidx[p] = qp;                            // dst-slot -> Z row (src-slot)
}

// ---- both layers' basis -> Bt (transposed bf16, zero-padded), one dispatch ----
__global__ __launch_bounds__(256) void split_bt_both(
        const float* __restrict__ basis1, ushort_t* __restrict__ Bt1,
        const float* __restrict__ basis2, ushort_t* __restrict__ Bt2) {
    int idx = blockIdx.x * 256 + threadIdx.x;
    const int n1 = OUTW * KP1;
    if (idx < n1) {
        int n = idx / KP1, k = idx - n * KP1;
        int b = n / HID, o = n - b * HID;
        float v = (k < IN_CH) ? basis1[((size_t)b * IN_CH + k) * HID + o] : 0.f;
        Bt1[idx] = f2bf_rne(v);
    } else {
        int i2 = idx - n1;
        if (i2 >= OUTW * KP2) return;
        int n = i2 / KP2, k = i2 - n * KP2;
        int b = n / HID, o = n - b * HID;
        float v = (k < HID) ? basis2[((size_t)b * HID + k) * HID + o] : 0.f;
        Bt2[i2] = f2bf_rne(v);
    }
}

// ---- MFMA GEMM: xbh[M,800](bf16) = A[M,K] * B[K,800] ----
// Barrier-free, LDS-free. BM=64, 512 threads = 8 waves (4 row-tiles x 2
// col-halves). A staged ONCE to registers as bf16 fragments (<=40 VGPR);
// B fragments read directly from L2-resident Bt (16B/lane in 64B rows --
// identical addresses across the 4 row-waves dedup in L1). Removes the 100
// stage->barrier->vmcnt(0)-drain cycles per block and cuts B restage
// traffic 640 MB -> 160 MB. K/RELU are template params so afrag indexing
// is compile-time static (no scratch).
template<int K, int RELU>
__global__ __launch_bounds__(512, 4) void gemm_mfma(
        const float* __restrict__ A, const ushort_t* __restrict__ Bt,
        ushort_t* __restrict__ xbh, int M) {
    constexpr int KSTEPS = (K + 31) / 32;     // 10 (layer1) / 4 (layer2)
    constexpr int KP = KSTEPS * 32;
    int tid  = threadIdx.x;
    int lane = tid & 63, wave = tid >> 6;     // 8 waves
    int wr = wave >> 1, wc = wave & 1;        // 4 row-groups x 2 col-halves
    int ml = lane & 15, quad = lane >> 4;
    int row0 = blockIdx.x * 64 + wr * 16;

    // ---- stage this wave's 16-row A tile straight into registers ----
    short8 afrag[KSTEPS];
    {
        int gr = row0 + ml;
        bool rowok = gr < M;
        const float* ar = A + (size_t)gr * K;
        #pragma unroll
        for (int ks = 0; ks < KSTEPS; ks++) {
            int kb = ks * 32 + quad * 8;
            float v[8];
            if (rowok && kb + 8 <= K) {
                float4 f0 = *(const float4*)&ar[kb];
                float4 f1 = *(const float4*)&ar[kb + 4];
                v[0]=f0.x; v[1]=f0.y; v[2]=f0.z; v[3]=f0.w;
                v[4]=f1.x; v[5]=f1.y; v[6]=f1.z; v[7]=f1.w;
            } else {
                #pragma unroll
                for (int i = 0; i < 8; i++)
                    v[i] = (rowok && kb + i < K) ? ar[kb + i] : 0.f;
            }
            if (RELU) {
                #pragma unroll
                for (int i = 0; i < 8; i++) v[i] = fmaxf(v[i], 0.f);
            }
            short8 hv;
            #pragma unroll
            for (int i = 0; i < 8; i++) hv[i] = (short)f2bf_rne(v[i]);
            afrag[ks] = hv;
        }
    }

    // ---- 5 column blocks of 160 (80 per col-half wave), K inner ----
    for (int cb = 0; cb < 5; cb++) {
        int col0 = cb * 160 + wc * 80;
        const ushort_t* bp0 = Bt + (size_t)(col0 + ml) * KP + quad * 8;
        f32x4 acc[5] = {};
        #pragma unroll
        for (int ks = 0; ks < KSTEPS; ks++) {
            short8 bf[5];
            #pragma unroll
            for (int nt = 0; nt < 5; nt++)
                bf[nt] = *(const short8*)(bp0 + (size_t)nt * 16 * KP + ks * 32);
            #pragma unroll
            for (int nt = 0; nt < 5; nt++)
                acc[nt] = __builtin_amdgcn_mfma_f32_16x16x32_bf16(
                              afrag[ks], bf[nt], acc[nt], 0, 0, 0);
        }
        // epilogue: bf16 store (C layout: row = quad*4 + r, col = nt*16 + ml)
        #pragma unroll
        for (int nt = 0; nt < 5; nt++) {
            #pragma unroll
            for (int r = 0; r < 4; r++) {
                int grow = row0 + quad * 4 + r;
                if (grow < M)
                    xbh[(size_t)grow * OUTW + col0 + nt * 16 + ml] =
                        f2bf_rne(acc[nt][r]);
            }
        }
    }
}

// ---- xbq[n,b] = xbh[n,b,:].q ; xbk likewise (reads bf16 xbh, coalesced) ----
__global__ __launch_bounds__(256) void qk3_kernel(
        const ushort_t* __restrict__ xbh, const float* __restrict__ q,
        const float* __restrict__ k, float* __restrict__ xbq,
        float* __restrict__ xbk) {
    __shared__ float sq[HID], sk[HID];
    int tid = threadIdx.x;
    if (tid < HID) { sq[tid] = q[tid]; sk[tid] = k[tid]; }
    __syncthreads();
    int idx = blockIdx.x * 256 + tid;     // idx = n*8 + b
    if (idx >= N_NODES * NB) return;
    const ushort_t* xr = xbh + (size_t)(idx >> 3) * OUTW + (idx & 7) * HID;
    float aq = 0.f, ak = 0.f;
    #pragma unroll
    for (int c = 0; c < 25; c++) {        // 25 x ushort4 (8B aligned)
        ushort4 v = *(const ushort4*)&xr[c * 4];
        #pragma unroll
        for (int i = 0; i < 4; i++) {
            float f = bf2f(((const ushort_t*)&v)[i]);
            aq = fmaf(f, sq[c * 4 + i], aq);
            ak = fmaf(f, sk[c * 4 + i], ak);
        }
    }
    xbq[idx] = aq;
    xbk[idx] = ak;
}

// ==== src-major, batched-4 Z rows; comp in LDS; keys via register window ====
// lane = eg*16 + c16; covers channels [8*c16, 8*c16+8) of edge p0+eg.
__global__ __launch_bounds__(256) void compute_z(
        const int* __restrict__ rowptr_s, const int* __restrict__ skey_s,
        const float* __restrict__ comp, const ushort_t* __restrict__ xbh,
        ushort_t* __restrict__ Z) {
    __shared__ float scomp[R_REL * NB];   // 1.6 KB
    int tid = threadIdx.x;
    for (int i = tid; i < R_REL * NB; i += 256) scomp[i] = comp[i];
    __syncthreads();
    int wave = tid >> 6, lane = tid & 63;
    int s = blockIdx.x * 4 + wave;
    if (s >= N_NODES) return;
    int beg = rowptr_s[s], end = rowptr_s[s + 1];
    if (beg == end) return;
    int eg = lane >> 4, c16 = lane & 15;
    int cbase = c16 * 8;
    float xr[NB][8];
    #pragma unroll
    for (int b = 0; b < NB; b++)
        #pragma unroll
        for (int i = 0; i < 8; i++) xr[b][i] = 0.f;
    if (cbase < HID) {
        #pragma unroll
        for (int b = 0; b < NB; b++) {
            const ushort_t* base = xbh + (size_t)s * OUTW + b * HID + cbase;
            ushort4 v0 = *(const ushort4*)base;       // 8B aligned
            xr[b][0] = bf2f(v0.x); xr[b][1] = bf2f(v0.y);
            xr[b][2] = bf2f(v0.z); xr[b][3] = bf2f(v0.w);
            if (cbase + 8 <= HID) {
                ushort4 v1 = *(const ushort4*)(base + 4);
                xr[b][4] = bf2f(v1.x); xr[b][5] = bf2f(v1.y);
                xr[b][6] = bf2f(v1.z); xr[b][7] = bf2f(v1.w);
            }
        }
    }
    for (int w0 = beg; w0 < end; w0 += 64) {
        // one coalesced key load covers the next 64 edges (16 quads)
        int kw = (w0 + lane < end) ? skey_s[w0 + lane] : 0;
        int wend = w0 + 64 < end ? w0 + 64 : end;
        for (int p0 = w0; p0 < wend; p0 += 4) {
            int j = p0 - w0 + eg;              // < 64 always
            int rt = __shfl(kw, j) & 63;       // zero memory ops in chain
            int p = p0 + eg;
            const float* cr = &scomp[rt * NB];
            float z[8] = {};
            #pragma unroll
            for (int b = 0; b < NB; b++) {
                float cb = cr[b];
                #pragma unroll
                for (int i = 0; i < 8; i++) z[i] = fmaf(cb, xr[b][i], z[i]);
            }
            ushort8 zz;
            #pragma unroll
            for (int i = 0; i < 8; i++) zz[i] = f2bf_rne(z[i]);
            if (p < end)
                *(ushort8*)&Z[(size_t)p * ZW + cbase] = zz;   // 16B, coalesced
        }
    }
}

// ==== dst-major: online softmax + paired-edge Z gather + bias; comp in LDS ====
__global__ __launch_bounds__(256) void msg_soft(
        const int* __restrict__ rowptr, const int* __restrict__ skey,
        const int* __restrict__ zidx,
        const float* __restrict__ comp, const ushort_t* __restrict__ Z,
        const float* __restrict__ xbq, const float* __restrict__ xbk,
        const float* __restrict__ bias, float* __restrict__ h) {
    __shared__ float scomp[R_REL * NB];   // 1.6 KB
    int tid = threadIdx.x;
    for (int i = tid; i < R_REL * NB; i += 256) scomp[i] = comp[i];
    __syncthreads();
    int wave = tid >> 6, lane = tid & 63;
    int d = blockIdx.x * 4 + wave;
    if (d >= N_NODES) return;
    int beg = rowptr[d], end = rowptr[d + 1];

    float4 qd0 = *(const float4*)&xbq[d * NB];
    float4 qd1 = *(const float4*)&xbq[d * NB + 4];

    int l5 = lane & 31;
    bool act = l5 < 25;
    int oc = l5 * 4;                  // channel base (4 channels per lane)
    f32x4 acc = {0.f, 0.f, 0.f, 0.f};
    float m = -1e30f, l = 0.f;

    for (int c0 = beg; c0 < end; c0 += 64) {
        int p = c0 + lane;
        bool valid = p < end;
        float a = -1e30f;
        int zi = 0;
        if (valid) {
            int key = skey[p];
            zi = zidx[p];
            int s = key >> 6, rt = key & 63;
            const float4 c0v = *(const float4*)&scomp[rt * NB];
            const float4 c1v = *(const float4*)&scomp[rt * NB + 4];
            const float4 k0v = *(const float4*)&xbk[s * NB];
            const float4 k1v = *(const float4*)&xbk[s * NB + 4];
            float qi = c0v.x*qd0.x + c0v.y*qd0.y + c0v.z*qd0.z + c0v.w*qd0.w
                     + c1v.x*qd1.x + c1v.y*qd1.y + c1v.z*qd1.z + c1v.w*qd1.w;
            float kj = c0v.x*k0v.x + c0v.y*k0v.y + c0v.z*k0v.z + c0v.w*k0v.w
                     + c1v.x*k1v.x + c1v.y*k1v.y + c1v.z*k1v.z + c1v.w*k1v.w;
            a = qi + kj;
            a = a > 0.f ? a : 0.2f * a;     // leaky_relu 0.2
        }
        float cm = a;
        #pragma unroll
        for (int off = 32; off; off >>= 1) cm = fmaxf(cm, __shfl_xor(cm, off));
        float M = fmaxf(m, cm);
        float scale = __expf(m - M);
        acc *= scale; l *= scale; m = M;
        float wgt = valid ? __expf(a - M) : 0.f;
        float cs = wgt;
        #pragma unroll
        for (int off = 32; off; off >>= 1) cs += __shfl_xor(cs, off);
        l += cs;
        int cnt = end - c0; if (cnt > 64) cnt = 64;
        for (int j = 0; j < cnt; j += 2) {
            int jj = j + (lane >> 5);         // even half: j, odd half: j+1
            float wj = __shfl(wgt, jj);       // invalid -> 0
            int   zj = __shfl(zi, jj);
            if (act) {
                ushort4 zz = *(const ushort4*)&Z[(size_t)zj * ZW + oc];
                acc.x = fmaf(wj, bf2f(zz.x), acc.x);
                acc.y = fmaf(wj, bf2f(zz.y), acc.y);
                acc.z = fmaf(wj, bf2f(zz.z), acc.z);
                acc.w = fmaf(wj, bf2f(zz.w), acc.w);
            }
        }
    }
    // combine even/odd-edge halves: lane ℓ (<25) += lane ℓ+32
    #pragma unroll
    for (int i = 0; i < 4; i++) acc[i] += __shfl_xor(acc[i], 32);
    if (lane < 25) {
        float inv = 1.f / (l + 1e-16f);
        float4 r;
        r.x = bias[oc]     + acc.x * inv;
        r.y = bias[oc + 1] + acc.y * inv;
        r.z = bias[oc + 2] + acc.z * inv;
        r.w = bias[oc + 3] + acc.w * inv;
        *(float4*)&h[(size_t)d * HID + oc] = r;   // 16B aligned (400|16)
    }
}

// ---- pooled = mean(relu(h2[qidx])); out = pooled @ Wl^T + bl ----
__global__ __launch_bounds__(128) void head_kernel(
        const float* __restrict__ h2, const int* __restrict__ qidx,
        const float* __restrict__ Wl, const float* __restrict__ bl,
        float* __restrict__ out) {
    __shared__ float pooled[HID];
    int tid = threadIdx.x;
    if (tid < HID) {
        float s = 0.f;
        for (int i = 0; i < NQ; i++)
            s += fmaxf(h2[(size_t)qidx[i] * HID + tid], 0.f);
        pooled[tid] = s * (1.0f / NQ);
    }
    __syncthreads();
    if (tid < CLS) {
        float s = bl[tid];
        for (int o = 0; o < HID; o++) s = fmaf(pooled[o], Wl[tid * HID + o], s);
        out[tid] = s;
    }
}

extern "C" void kernel_launch(void* const* d_in, const int* in_sizes, int n_in,
                              void* d_out, int out_size, void* d_ws, size_t ws_size,
                              hipStream_t stream) {
    const float* x      = (const float*)d_in[0];
    const int*   ei     = (const int*)  d_in[1];
    const int*   et     = (const int*)  d_in[2];
    const int*   qidx   = (const int*)  d_in[3];
    const float* comp1  = (const float*)d_in[4];
    const float* basis1 = (const float*)d_in[5];
    const float* q1     = (const float*)d_in[6];
    const float* k1     = (const float*)d_in[7];
    const float* b1     = (const float*)d_in[8];
    const float* comp2  = (const float*)d_in[9];
    const float* basis2 = (const float*)d_in[10];
    const float* q2     = (const float*)d_in[11];
    const float* k2     = (const float*)d_in[12];
    const float* b2     = (const float*)d_in[13];
    const float* Wl     = (const float*)d_in[14];
    const float* bl     = (const float*)d_in[15];
    float* out = (float*)d_out;

    char* w = (char*)d_ws;
    size_t off = 0;
    auto alloc = [&](size_t nbytes) {
        void* p = (void*)(w + off);
        off += ((nbytes + 255) / 256) * 256;
        return p;
    };
    ushort_t* xbh    = (ushort_t*)alloc((size_t)N_NODES * OUTW * 2); // 32 MB
    ushort_t* Z      = (ushort_t*)alloc((size_t)E_EDGES * ZW * 2);   // 82 MB
    float*    h1     = (float*)alloc((size_t)N_NODES * HID * 4);     // 8 MB
    float*    h2     = (float*)alloc((size_t)N_NODES * HID * 4);     // 8 MB
    ushort_t* Bt1    = (ushort_t*)alloc((size_t)OUTW * KP1 * 2);     // 512 KB
    ushort_t* Bt2    = (ushort_t*)alloc((size_t)OUTW * KP2 * 2);     // 205 KB
    float*    xbq    = (float*)alloc((size_t)N_NODES * NB * 4);
    float*    xbk    = (float*)alloc((size_t)N_NODES * NB * 4);
    int*      deg_d  = (int*)alloc(N_NODES * 4);
    int*      deg_s  = (int*)alloc(N_NODES * 4);
    int*      rp_d   = (int*)alloc((N_NODES + 1) * 4);
    int*      rp_s   = (int*)alloc((N_NODES + 1) * 4);
    int*      cur_d  = (int*)alloc(N_NODES * 4);
    int*      cur_s  = (int*)alloc(N_NODES * 4);
    int*      bsum_d = (int*)alloc(SCAN_BLKS * 4);
    int*      bsum_s = (int*)alloc(SCAN_BLKS * 4);
    int*      skey   = (int*)alloc(E_EDGES * 4);
    int*      skey_s = (int*)alloc(E_EDGES * 4);
    int*      zidx   = (int*)alloc(E_EDGES * 4);

    // ---- CSR build (once; same graph both layers) + both Bt upfront ----
    zero_deg2<<<SCAN_BLKS, 256, 0, stream>>>(deg_d, deg_s);
    hist2_kernel<<<(E_EDGES + 255) / 256, 256, 0, stream>>>(ei, deg_d, deg_s);
    scan1_both<<<2 * SCAN_BLKS, 256, 0, stream>>>(deg_d, rp_d, bsum_d, deg_s, rp_s, bsum_s);
    scan2_both<<<2, 128, 0, stream>>>(bsum_d, rp_d, bsum_s, rp_s);
    scan3_both<<<2 * SCAN_BLKS, 256, 0, stream>>>(rp_d, bsum_d, cur_d, rp_s, bsum_s, cur_s);
    scatter_both<<<(E_EDGES + 255) / 256, 256, 0, stream>>>(ei, et, cur_d, cur_s, skey, skey_s, zidx);
    split_bt_both<<<(OUTW * (KP1 + KP2) + 255) / 256, 256, 0, stream>>>(basis1, Bt1, basis2, Bt2);

    const int GGRID = (N_NODES + 63) / 64;   // 313 blocks, 8 waves each

    // ---- layer 1 ----
    gemm_mfma<IN_CH, 0><<<GGRID, 512, 0, stream>>>(x, Bt1, xbh, N_NODES);
    qk3_kernel<<<(N_NODES * NB + 255) / 256, 256, 0, stream>>>(xbh, q1, k1, xbq, xbk);
    compute_z<<<(N_NODES + 3) / 4, 256, 0, stream>>>(rp_s, skey_s, comp1, xbh, Z);
    msg_soft<<<(N_NODES + 3) / 4, 256, 0, stream>>>(rp_d, skey, zidx, comp1, Z, xbq, xbk, b1, h1);

    // ---- layer 2 ----
    gemm_mfma<HID, 1><<<GGRID, 512, 0, stream>>>(h1, Bt2, xbh, N_NODES);
    qk3_kernel<<<(N_NODES * NB + 255) / 256, 256, 0, stream>>>(xbh, q2, k2, xbq, xbk);
    compute_z<<<(N_NODES + 3) / 4, 256, 0, stream>>>(rp_s, skey_s, comp2, xbh, Z);
    msg_soft<<<(N_NODES + 3) / 4, 256, 0, stream>>>(rp_d, skey, zidx, comp2, Z, xbq, xbk, b2, h2);

    head_kernel<<<1, 128, 0, stream>>>(h2, qidx, Wl, bl, out);
}

// Round 2
// 380.036 us; speedup vs baseline: 1.2592x; 1.2592x over previous
//
#include <hip/hip_runtime.h>
#include <math.h>

#define N_NODES 20000
#define E_EDGES 320000
#define IN_CH   300
#define HID     100
#define R_REL   50
#define NB      8
#define CLS     3
#define NQ      64
#define OUTW    800   // NB * HID
#define ZW      128   // Z row stride (ushorts): 256-B rows, batched-4 writes
#define KP1     320
#define KP2     128
#define MPAD    20224 // 79 * 256 (row-chunk padded M for A bf16 buffers)
#define NPAIR   79    // MPAD / 256
#define GEMM_RG 25    // row-groups; grid = 10 col-blocks * 25 = 250 blocks
#define SCAN_BLKS ((N_NODES + 255) / 256)   // 79

typedef unsigned short ushort_t;
typedef __attribute__((ext_vector_type(8))) short     short8;
typedef __attribute__((ext_vector_type(8))) unsigned short ushort8;
typedef __attribute__((ext_vector_type(4))) float     f32x4;
typedef __attribute__((ext_vector_type(2))) float     f32x2;

__device__ __forceinline__ ushort_t f2bf_rne(float f) {   // round-nearest-even
    unsigned u = __float_as_uint(f);
    unsigned r = (u + 0x7fffu + ((u >> 16) & 1u)) >> 16;
    return (ushort_t)r;
}
__device__ __forceinline__ float bf2f(ushort_t u) {
    return __uint_as_float((unsigned)u << 16);
}

// ============================ CSR build =================================
__global__ __launch_bounds__(256) void zero_deg2(int* __restrict__ dd,
                                                 int* __restrict__ ds) {
    int i = blockIdx.x * 256 + threadIdx.x;
    if (i < N_NODES) { dd[i] = 0; ds[i] = 0; }
}

__global__ __launch_bounds__(256) void hist2_kernel(
        const int* __restrict__ ei, int* __restrict__ dd,
        int* __restrict__ ds) {
    int e = blockIdx.x * 256 + threadIdx.x;
    if (e < E_EDGES) {
        atomicAdd(&dd[ei[E_EDGES + e]], 1);
        atomicAdd(&ds[ei[e]], 1);
    }
}

// dual-set scans: blockIdx selects (deg_d...) or (deg_s...) set
__global__ __launch_bounds__(256) void scan1_both(
        const int* __restrict__ deg_d, int* __restrict__ rp_d, int* __restrict__ bsum_d,
        const int* __restrict__ deg_s, int* __restrict__ rp_s, int* __restrict__ bsum_s) {
    int set = blockIdx.x / SCAN_BLKS, blk = blockIdx.x % SCAN_BLKS;
    const int* deg = set ? deg_s : deg_d;
    int* rowptr    = set ? rp_s  : rp_d;
    int* bsum      = set ? bsum_s : bsum_d;
    __shared__ int s[256];
    int tid = threadIdx.x;
    int idx = blk * 256 + tid;
    int v = (idx < N_NODES) ? deg[idx] : 0;
    s[tid] = v; __syncthreads();
    #pragma unroll
    for (int off = 1; off < 256; off <<= 1) {
        int t = (tid >= off) ? s[tid - off] : 0;
        __syncthreads();
        s[tid] += t;
        __syncthreads();
    }
    if (idx < N_NODES) rowptr[idx] = s[tid] - v;   // exclusive
    if (tid == 255) bsum[blk] = s[255];
}

__global__ __launch_bounds__(128) void scan2_both(
        int* __restrict__ bsum_d, int* __restrict__ rp_d,
        int* __restrict__ bsum_s, int* __restrict__ rp_s) {
    int* bsum   = blockIdx.x ? bsum_s : bsum_d;
    int* rowptr = blockIdx.x ? rp_s   : rp_d;
    __shared__ int s[128];
    int tid = threadIdx.x;
    int v = (tid < SCAN_BLKS) ? bsum[tid] : 0;
    s[tid] = v; __syncthreads();
    #pragma unroll
    for (int off = 1; off < 128; off <<= 1) {
        int t = (tid >= off) ? s[tid - off] : 0;
        __syncthreads();
        s[tid] += t;
        __syncthreads();
    }
    if (tid < SCAN_BLKS) bsum[tid] = s[tid] - v;   // exclusive
    if (tid == 0) rowptr[N_NODES] = E_EDGES;
}

__global__ __launch_bounds__(256) void scan3_both(
        int* __restrict__ rp_d, const int* __restrict__ bsum_d, int* __restrict__ cur_d,
        int* __restrict__ rp_s, const int* __restrict__ bsum_s, int* __restrict__ cur_s) {
    int set = blockIdx.x / SCAN_BLKS, blk = blockIdx.x % SCAN_BLKS;
    int* rowptr      = set ? rp_s   : rp_d;
    const int* bsum  = set ? bsum_s : bsum_d;
    int* cursor      = set ? cur_s  : cur_d;
    int idx = blk * 256 + threadIdx.x;
    if (idx < N_NODES) {
        int v = rowptr[idx] + bsum[blk];
        rowptr[idx] = v;
        cursor[idx] = v;
    }
}

// fused scatter: dst-CSR key (src,rel), src-CSR key (rel), and zidx map
__global__ __launch_bounds__(256) void scatter_both(
        const int* __restrict__ ei, const int* __restrict__ et,
        int* __restrict__ cur_d, int* __restrict__ cur_s,
        int* __restrict__ skey, int* __restrict__ skey_s,
        int* __restrict__ zidx) {
    int e = blockIdx.x * 256 + threadIdx.x;
    if (e >= E_EDGES) return;
    int s = ei[e], d = ei[E_EDGES + e], rt = et[e];
    int p = atomicAdd(&cur_d[d], 1);
    skey[p] = (s << 6) | rt;                 // dst-order: (src, rel)
    int qp = atomicAdd(&cur_s[s], 1);
    skey_s[qp] = rt;                         // src-order: rel only
    zidx[p] = qp;                            // dst-slot -> Z row (src-slot)
}

// ---- both layers' basis -> Bt (transposed bf16, zero-padded), one dispatch ----
__global__ __launch_bounds__(256) void split_bt_both(
        const float* __restrict__ basis1, ushort_t* __restrict__ Bt1,
        const float* __restrict__ basis2, ushort_t* __restrict__ Bt2) {
    int idx = blockIdx.x * 256 + threadIdx.x;
    const int n1 = OUTW * KP1;
    if (idx < n1) {
        int n = idx / KP1, k = idx - n * KP1;
        int b = n / HID, o = n - b * HID;
        float v = (k < IN_CH) ? basis1[((size_t)b * IN_CH + k) * HID + o] : 0.f;
        Bt1[idx] = f2bf_rne(v);
    } else {
        int i2 = idx - n1;
        if (i2 >= OUTW * KP2) return;
        int n = i2 / KP2, k = i2 - n * KP2;
        int b = n / HID, o = n - b * HID;
        float v = (k < HID) ? basis2[((size_t)b * HID + k) * HID + o] : 0.f;
        Bt2[i2] = f2bf_rne(v);
    }
}

// ---- A (f32, [M,K]) -> bf16 [MPAD, KP] zero-padded (K tail, M tail), opt relu ----
// Memory-bound pre-pass: removes f32->bf16 conversion from the GEMM's
// critical path and halves the GEMM's A bytes.
template<int K, int KP, int RELU>
__global__ __launch_bounds__(256) void cvt_pad_bf16(
        const float* __restrict__ in, ushort_t* __restrict__ out, int M) {
    constexpr int CH = KP / 8;
    int idx = blockIdx.x * 256 + threadIdx.x;
    if (idx >= MPAD * CH) return;
    int n = idx / CH, c = idx - n * CH;
    int k = c * 8;
    float v[8];
    if (n < M && k + 8 <= K) {
        float4 f0 = *(const float4*)&in[(size_t)n * K + k];
        float4 f1 = *(const float4*)&in[(size_t)n * K + k + 4];
        v[0]=f0.x; v[1]=f0.y; v[2]=f0.z; v[3]=f0.w;
        v[4]=f1.x; v[5]=f1.y; v[6]=f1.z; v[7]=f1.w;
    } else {
        #pragma unroll
        for (int i = 0; i < 8; i++)
            v[i] = (n < M && k + i < K) ? in[(size_t)n * K + k + i] : 0.f;
    }
    if (RELU) {
        #pragma unroll
        for (int i = 0; i < 8; i++) v[i] = fmaxf(v[i], 0.f);
    }
    ushort8 hv;
    #pragma unroll
    for (int i = 0; i < 8; i++) hv[i] = f2bf_rne(v[i]);
    *(ushort8*)&out[(size_t)n * KP + k] = hv;
}

// ---- MFMA GEMM: xbh[M,800](bf16) = Ab[M,KP](bf16) * B[KP,800] ----
// 250 blocks = 10 col-blocks (80 cols) x 25 row-groups, 512 threads.
// Each block stages its 80 x KP B tile into LDS ONCE (pad stride SW=KP+8:
// ml-stride = 4 banks mod 32 -> 8 accesses/bank = conflict-free minimum),
// one barrier, then a barrier-free row-chunk loop: 8 waves x 32 rows each
// (2 sub-tiles of 16). A frags load up front (20 independent 16B loads),
// latency hidden by the co-resident wave's MFMAs + compiler pipelining.
// ds_read:MFMA = 1:2 so LDS BW is below the MFMA-pipe demand.
template<int KP>
__global__ __launch_bounds__(512, 2) void gemm_mfma(
        const ushort_t* __restrict__ Ab, const ushort_t* __restrict__ Bt,
        ushort_t* __restrict__ xbh, int M) {
    constexpr int KSTEPS = KP / 32;           // 10 (layer1) / 4 (layer2)
    constexpr int SW = KP + 8;                // LDS col stride (ushorts)
    constexpr int CH = KP / 8;
    __shared__ ushort_t Bs[80 * SW];          // 52.5 KB (L1) / 21.3 KB (L2)
    int tid = threadIdx.x, lane = tid & 63, wave = tid >> 6;
    int ml = lane & 15, quad = lane >> 4;
    int cb = blockIdx.x / GEMM_RG;            // 10 col blocks of 80
    int rg = blockIdx.x - cb * GEMM_RG;
    int col0 = cb * 80;

    // ---- stage B tile once (coalesced 16B chunks) ----
    for (int t = tid; t < 80 * CH; t += 512) {
        int c = t / CH, ch = t - c * CH;
        *(ushort8*)&Bs[c * SW + ch * 8] =
            *(const ushort8*)&Bt[(size_t)(col0 + c) * KP + ch * 8];
    }
    __syncthreads();                          // the ONLY barrier

    const ushort_t* bb = &Bs[(size_t)ml * SW + quad * 8];

    for (int g = rg; g < NPAIR; g += GEMM_RG) {
        int rbase = g * 256 + wave * 32;      // this wave's 32 rows
        const ushort_t* ar0 = Ab + (size_t)(rbase + ml) * KP + quad * 8;
        const ushort_t* ar1 = ar0 + (size_t)16 * KP;
        short8 a0[KSTEPS], a1[KSTEPS];
        #pragma unroll
        for (int ks = 0; ks < KSTEPS; ks++) {
            a0[ks] = *(const short8*)(ar0 + ks * 32);
            a1[ks] = *(const short8*)(ar1 + ks * 32);
        }
        f32x4 acc0[5] = {}, acc1[5] = {};
        #pragma unroll
        for (int ks = 0; ks < KSTEPS; ks++) {
            short8 bf[5];
            #pragma unroll
            for (int nt = 0; nt < 5; nt++)
                bf[nt] = *(const short8*)(bb + nt * 16 * SW + ks * 32);
            #pragma unroll
            for (int nt = 0; nt < 5; nt++) {
                acc0[nt] = __builtin_amdgcn_mfma_f32_16x16x32_bf16(
                               a0[ks], bf[nt], acc0[nt], 0, 0, 0);
                acc1[nt] = __builtin_amdgcn_mfma_f32_16x16x32_bf16(
                               a1[ks], bf[nt], acc1[nt], 0, 0, 0);
            }
        }
        // epilogue (C layout: row = quad*4 + r, col = nt*16 + ml)
        #pragma unroll
        for (int nt = 0; nt < 5; nt++) {
            #pragma unroll
            for (int r = 0; r < 4; r++) {
                int g0 = rbase + quad * 4 + r;
                if (g0 < M)
                    xbh[(size_t)g0 * OUTW + col0 + nt * 16 + ml] =
                        f2bf_rne(acc0[nt][r]);
                int g1 = g0 + 16;
                if (g1 < M)
                    xbh[(size_t)g1 * OUTW + col0 + nt * 16 + ml] =
                        f2bf_rne(acc1[nt][r]);
            }
        }
    }
}

// ---- xbq[n,b] = xbh[n,b,:].q ; xbk likewise (reads bf16 xbh, coalesced) ----
__global__ __launch_bounds__(256) void qk3_kernel(
        const ushort_t* __restrict__ xbh, const float* __restrict__ q,
        const float* __restrict__ k, float* __restrict__ xbq,
        float* __restrict__ xbk) {
    __shared__ float sq[HID], sk[HID];
    int tid = threadIdx.x;
    if (tid < HID) { sq[tid] = q[tid]; sk[tid] = k[tid]; }
    __syncthreads();
    int idx = blockIdx.x * 256 + tid;     // idx = n*8 + b
    if (idx >= N_NODES * NB) return;
    const ushort_t* xr = xbh + (size_t)(idx >> 3) * OUTW + (idx & 7) * HID;
    float aq = 0.f, ak = 0.f;
    #pragma unroll
    for (int c = 0; c < 25; c++) {        // 25 x ushort4 (8B aligned)
        ushort4 v = *(const ushort4*)&xr[c * 4];
        #pragma unroll
        for (int i = 0; i < 4; i++) {
            float f = bf2f(((const ushort_t*)&v)[i]);
            aq = fmaf(f, sq[c * 4 + i], aq);
            ak = fmaf(f, sk[c * 4 + i], ak);
        }
    }
    xbq[idx] = aq;
    xbk[idx] = ak;
}

// ==== src-major, batched-4 Z rows; comp in LDS; keys via register window ====
// lane = eg*16 + c16; covers channels [8*c16, 8*c16+8) of edge p0+eg.
__global__ __launch_bounds__(256) void compute_z(
        const int* __restrict__ rowptr_s, const int* __restrict__ skey_s,
        const float* __restrict__ comp, const ushort_t* __restrict__ xbh,
        ushort_t* __restrict__ Z) {
    __shared__ float scomp[R_REL * NB];   // 1.6 KB
    int tid = threadIdx.x;
    for (int i = tid; i < R_REL * NB; i += 256) scomp[i] = comp[i];
    __syncthreads();
    int wave = tid >> 6, lane = tid & 63;
    int s = blockIdx.x * 4 + wave;
    if (s >= N_NODES) return;
    int beg = rowptr_s[s], end = rowptr_s[s + 1];
    if (beg == end) return;
    int eg = lane >> 4, c16 = lane & 15;
    int cbase = c16 * 8;
    float xr[NB][8];
    #pragma unroll
    for (int b = 0; b < NB; b++)
        #pragma unroll
        for (int i = 0; i < 8; i++) xr[b][i] = 0.f;
    if (cbase < HID) {
        #pragma unroll
        for (int b = 0; b < NB; b++) {
            const ushort_t* base = xbh + (size_t)s * OUTW + b * HID + cbase;
            ushort4 v0 = *(const ushort4*)base;       // 8B aligned
            xr[b][0] = bf2f(v0.x); xr[b][1] = bf2f(v0.y);
            xr[b][2] = bf2f(v0.z); xr[b][3] = bf2f(v0.w);
            if (cbase + 8 <= HID) {
                ushort4 v1 = *(const ushort4*)(base + 4);
                xr[b][4] = bf2f(v1.x); xr[b][5] = bf2f(v1.y);
                xr[b][6] = bf2f(v1.z); xr[b][7] = bf2f(v1.w);
            }
        }
    }
    for (int w0 = beg; w0 < end; w0 += 64) {
        // one coalesced key load covers the next 64 edges (16 quads)
        int kw = (w0 + lane < end) ? skey_s[w0 + lane] : 0;
        int wend = w0 + 64 < end ? w0 + 64 : end;
        for (int p0 = w0; p0 < wend; p0 += 4) {
            int j = p0 - w0 + eg;              // < 64 always
            int rt = __shfl(kw, j) & 63;       // zero memory ops in chain
            int p = p0 + eg;
            const float* cr = &scomp[rt * NB];
            float z[8] = {};
            #pragma unroll
            for (int b = 0; b < NB; b++) {
                float cb = cr[b];
                #pragma unroll
                for (int i = 0; i < 8; i++) z[i] = fmaf(cb, xr[b][i], z[i]);
            }
            ushort8 zz;
            #pragma unroll
            for (int i = 0; i < 8; i++) zz[i] = f2bf_rne(z[i]);
            if (p < end)
                *(ushort8*)&Z[(size_t)p * ZW + cbase] = zz;   // 16B, coalesced
        }
    }
}

// ==== dst-major: online softmax + paired-edge Z gather + bias; comp in LDS ====
__global__ __launch_bounds__(256) void msg_soft(
        const int* __restrict__ rowptr, const int* __restrict__ skey,
        const int* __restrict__ zidx,
        const float* __restrict__ comp, const ushort_t* __restrict__ Z,
        const float* __restrict__ xbq, const float* __restrict__ xbk,
        const float* __restrict__ bias, float* __restrict__ h) {
    __shared__ float scomp[R_REL * NB];   // 1.6 KB
    int tid = threadIdx.x;
    for (int i = tid; i < R_REL * NB; i += 256) scomp[i] = comp[i];
    __syncthreads();
    int wave = tid >> 6, lane = tid & 63;
    int d = blockIdx.x * 4 + wave;
    if (d >= N_NODES) return;
    int beg = rowptr[d], end = rowptr[d + 1];

    float4 qd0 = *(const float4*)&xbq[d * NB];
    float4 qd1 = *(const float4*)&xbq[d * NB + 4];

    int l5 = lane & 31;
    bool act = l5 < 25;
    int oc = l5 * 4;                  // channel base (4 channels per lane)
    f32x4 acc = {0.f, 0.f, 0.f, 0.f};
    float m = -1e30f, l = 0.f;

    for (int c0 = beg; c0 < end; c0 += 64) {
        int p = c0 + lane;
        bool valid = p < end;
        float a = -1e30f;
        int zi = 0;
        if (valid) {
            int key = skey[p];
            zi = zidx[p];
            int s = key >> 6, rt = key & 63;
            const float4 c0v = *(const float4*)&scomp[rt * NB];
            const float4 c1v = *(const float4*)&scomp[rt * NB + 4];
            const float4 k0v = *(const float4*)&xbk[s * NB];
            const float4 k1v = *(const float4*)&xbk[s * NB + 4];
            float qi = c0v.x*qd0.x + c0v.y*qd0.y + c0v.z*qd0.z + c0v.w*qd0.w
                     + c1v.x*qd1.x + c1v.y*qd1.y + c1v.z*qd1.z + c1v.w*qd1.w;
            float kj = c0v.x*k0v.x + c0v.y*k0v.y + c0v.z*k0v.z + c0v.w*k0v.w
                     + c1v.x*k1v.x + c1v.y*k1v.y + c1v.z*k1v.z + c1v.w*k1v.w;
            a = qi + kj;
            a = a > 0.f ? a : 0.2f * a;     // leaky_relu 0.2
        }
        float cm = a;
        #pragma unroll
        for (int off = 32; off; off >>= 1) cm = fmaxf(cm, __shfl_xor(cm, off));
        float M = fmaxf(m, cm);
        float scale = __expf(m - M);
        acc *= scale; l *= scale; m = M;
        float wgt = valid ? __expf(a - M) : 0.f;
        float cs = wgt;
        #pragma unroll
        for (int off = 32; off; off >>= 1) cs += __shfl_xor(cs, off);
        l += cs;
        int cnt = end - c0; if (cnt > 64) cnt = 64;
        for (int j = 0; j < cnt; j += 2) {
            int jj = j + (lane >> 5);         // even half: j, odd half: j+1
            float wj = __shfl(wgt, jj);       // invalid -> 0
            int   zj = __shfl(zi, jj);
            if (act) {
                ushort4 zz = *(const ushort4*)&Z[(size_t)zj * ZW + oc];
                acc.x = fmaf(wj, bf2f(zz.x), acc.x);
                acc.y = fmaf(wj, bf2f(zz.y), acc.y);
                acc.z = fmaf(wj, bf2f(zz.z), acc.z);
                acc.w = fmaf(wj, bf2f(zz.w), acc.w);
            }
        }
    }
    // combine even/odd-edge halves: lane ℓ (<25) += lane ℓ+32
    #pragma unroll
    for (int i = 0; i < 4; i++) acc[i] += __shfl_xor(acc[i], 32);
    if (lane < 25) {
        float inv = 1.f / (l + 1e-16f);
        float4 r;
        r.x = bias[oc]     + acc.x * inv;
        r.y = bias[oc + 1] + acc.y * inv;
        r.z = bias[oc + 2] + acc.z * inv;
        r.w = bias[oc + 3] + acc.w * inv;
        *(float4*)&h[(size_t)d * HID + oc] = r;   // 16B aligned (400|16)
    }
}

// ---- pooled = mean(relu(h2[qidx])); out = pooled @ Wl^T + bl ----
__global__ __launch_bounds__(128) void head_kernel(
        const float* __restrict__ h2, const int* __restrict__ qidx,
        const float* __restrict__ Wl, const float* __restrict__ bl,
        float* __restrict__ out) {
    __shared__ float pooled[HID];
    int tid = threadIdx.x;
    if (tid < HID) {
        float s = 0.f;
        for (int i = 0; i < NQ; i++)
            s += fmaxf(h2[(size_t)qidx[i] * HID + tid], 0.f);
        pooled[tid] = s * (1.0f / NQ);
    }
    __syncthreads();
    if (tid < CLS) {
        float s = bl[tid];
        for (int o = 0; o < HID; o++) s = fmaf(pooled[o], Wl[tid * HID + o], s);
        out[tid] = s;
    }
}

extern "C" void kernel_launch(void* const* d_in, const int* in_sizes, int n_in,
                              void* d_out, int out_size, void* d_ws, size_t ws_size,
                              hipStream_t stream) {
    const float* x      = (const float*)d_in[0];
    const int*   ei     = (const int*)  d_in[1];
    const int*   et     = (const int*)  d_in[2];
    const int*   qidx   = (const int*)  d_in[3];
    const float* comp1  = (const float*)d_in[4];
    const float* basis1 = (const float*)d_in[5];
    const float* q1     = (const float*)d_in[6];
    const float* k1     = (const float*)d_in[7];
    const float* b1     = (const float*)d_in[8];
    const float* comp2  = (const float*)d_in[9];
    const float* basis2 = (const float*)d_in[10];
    const float* q2     = (const float*)d_in[11];
    const float* k2     = (const float*)d_in[12];
    const float* b2     = (const float*)d_in[13];
    const float* Wl     = (const float*)d_in[14];
    const float* bl     = (const float*)d_in[15];
    float* out = (float*)d_out;

    char* w = (char*)d_ws;
    size_t off = 0;
    auto alloc = [&](size_t nbytes) {
        void* p = (void*)(w + off);
        off += ((nbytes + 255) / 256) * 256;
        return p;
    };
    ushort_t* xbh    = (ushort_t*)alloc((size_t)N_NODES * OUTW * 2); // 32 MB
    ushort_t* Z      = (ushort_t*)alloc((size_t)E_EDGES * ZW * 2);   // 82 MB
    float*    h1     = (float*)alloc((size_t)N_NODES * HID * 4);     // 8 MB
    float*    h2     = (float*)alloc((size_t)N_NODES * HID * 4);     // 8 MB
    ushort_t* Bt1    = (ushort_t*)alloc((size_t)OUTW * KP1 * 2);     // 512 KB
    ushort_t* Bt2    = (ushort_t*)alloc((size_t)OUTW * KP2 * 2);     // 205 KB
    ushort_t* xbA    = (ushort_t*)alloc((size_t)MPAD * KP1 * 2);     // 12.9 MB
    ushort_t* hbA    = (ushort_t*)alloc((size_t)MPAD * KP2 * 2);     // 5.2 MB
    float*    xbq    = (float*)alloc((size_t)N_NODES * NB * 4);
    float*    xbk    = (float*)alloc((size_t)N_NODES * NB * 4);
    int*      deg_d  = (int*)alloc(N_NODES * 4);
    int*      deg_s  = (int*)alloc(N_NODES * 4);
    int*      rp_d   = (int*)alloc((N_NODES + 1) * 4);
    int*      rp_s   = (int*)alloc((N_NODES + 1) * 4);
    int*      cur_d  = (int*)alloc(N_NODES * 4);
    int*      cur_s  = (int*)alloc(N_NODES * 4);
    int*      bsum_d = (int*)alloc(SCAN_BLKS * 4);
    int*      bsum_s = (int*)alloc(SCAN_BLKS * 4);
    int*      skey   = (int*)alloc(E_EDGES * 4);
    int*      skey_s = (int*)alloc(E_EDGES * 4);
    int*      zidx   = (int*)alloc(E_EDGES * 4);

    // ---- CSR build (once; same graph both layers) + both Bt + A1 upfront ----
    zero_deg2<<<SCAN_BLKS, 256, 0, stream>>>(deg_d, deg_s);
    hist2_kernel<<<(E_EDGES + 255) / 256, 256, 0, stream>>>(ei, deg_d, deg_s);
    scan1_both<<<2 * SCAN_BLKS, 256, 0, stream>>>(deg_d, rp_d, bsum_d, deg_s, rp_s, bsum_s);
    scan2_both<<<2, 128, 0, stream>>>(bsum_d, rp_d, bsum_s, rp_s);
    scan3_both<<<2 * SCAN_BLKS, 256, 0, stream>>>(rp_d, bsum_d, cur_d, rp_s, bsum_s, cur_s);
    scatter_both<<<(E_EDGES + 255) / 256, 256, 0, stream>>>(ei, et, cur_d, cur_s, skey, skey_s, zidx);
    split_bt_both<<<(OUTW * (KP1 + KP2) + 255) / 256, 256, 0, stream>>>(basis1, Bt1, basis2, Bt2);
    cvt_pad_bf16<IN_CH, KP1, 0><<<(MPAD * (KP1 / 8) + 255) / 256, 256, 0, stream>>>(x, xbA, N_NODES);

    // ---- layer 1 ----
    gemm_mfma<KP1><<<10 * GEMM_RG, 512, 0, stream>>>(xbA, Bt1, xbh, N_NODES);
    qk3_kernel<<<(N_NODES * NB + 255) / 256, 256, 0, stream>>>(xbh, q1, k1, xbq, xbk);
    compute_z<<<(N_NODES + 3) / 4, 256, 0, stream>>>(rp_s, skey_s, comp1, xbh, Z);
    msg_soft<<<(N_NODES + 3) / 4, 256, 0, stream>>>(rp_d, skey, zidx, comp1, Z, xbq, xbk, b1, h1);

    // ---- layer 2 ----
    cvt_pad_bf16<HID, KP2, 1><<<(MPAD * (KP2 / 8) + 255) / 256, 256, 0, stream>>>(h1, hbA, N_NODES);
    gemm_mfma<KP2><<<10 * GEMM_RG, 512, 0, stream>>>(hbA, Bt2, xbh, N_NODES);
    qk3_kernel<<<(N_NODES * NB + 255) / 256, 256, 0, stream>>>(xbh, q2, k2, xbq, xbk);
    compute_z<<<(N_NODES + 3) / 4, 256, 0, stream>>>(rp_s, skey_s, comp2, xbh, Z);
    msg_soft<<<(N_NODES + 3) / 4, 256, 0, stream>>>(rp_d, skey, zidx, comp2, Z, xbq, xbk, b2, h2);

    head_kernel<<<1, 128, 0, stream>>>(h2, qidx, Wl, bl, out);
}

// Round 3
// 378.868 us; speedup vs baseline: 1.2631x; 1.0031x over previous
//
#include <hip/hip_runtime.h>
#include <math.h>

#define N_NODES 20000
#define E_EDGES 320000
#define IN_CH   300
#define HID     100
#define R_REL   50
#define NB      8
#define CLS     3
#define NQ      64
#define OUTW    800   // NB * HID
#define ZW      128   // Z row stride (ushorts): 256-B rows, batched-4 writes
#define KP1     320
#define KP2     128
#define MPAD    20224 // 79 * 256 (row-chunk padded M for A bf16 buffers)
#define NPAIR   79    // MPAD / 256
#define GEMM_RG 48    // row-groups; grid = 10 col-blocks * 48 = 480 blocks
#define SCAN_BLKS ((N_NODES + 255) / 256)   // 79

typedef unsigned short ushort_t;
typedef __attribute__((ext_vector_type(8))) short     short8;
typedef __attribute__((ext_vector_type(8))) unsigned short ushort8;
typedef __attribute__((ext_vector_type(4))) float     f32x4;
typedef __attribute__((ext_vector_type(2))) float     f32x2;

__device__ __forceinline__ ushort_t f2bf_rne(float f) {   // round-nearest-even
    unsigned u = __float_as_uint(f);
    unsigned r = (u + 0x7fffu + ((u >> 16) & 1u)) >> 16;
    return (ushort_t)r;
}
__device__ __forceinline__ float bf2f(ushort_t u) {
    return __uint_as_float((unsigned)u << 16);
}

// ============================ CSR build =================================
__global__ __launch_bounds__(256) void zero_deg2(int* __restrict__ dd,
                                                 int* __restrict__ ds) {
    int i = blockIdx.x * 256 + threadIdx.x;
    if (i < N_NODES) { dd[i] = 0; ds[i] = 0; }
}

// zero the padded bf16 layer-2 A buffer (pads must be 0; body overwritten
// by msg_soft<1> before gemm reads it)
__global__ __launch_bounds__(256) void zero_hbA(ushort_t* __restrict__ p) {
    int i = blockIdx.x * 256 + threadIdx.x;
    if (i < MPAD * KP2 / 8) {
        ushort8 z = {};
        *(ushort8*)&p[(size_t)i * 8] = z;
    }
}

__global__ __launch_bounds__(256) void hist2_kernel(
        const int* __restrict__ ei, int* __restrict__ dd,
        int* __restrict__ ds) {
    int e = blockIdx.x * 256 + threadIdx.x;
    if (e < E_EDGES) {
        atomicAdd(&dd[ei[E_EDGES + e]], 1);
        atomicAdd(&ds[ei[e]], 1);
    }
}

// dual-set scans: blockIdx selects (deg_d...) or (deg_s...) set
__global__ __launch_bounds__(256) void scan1_both(
        const int* __restrict__ deg_d, int* __restrict__ rp_d, int* __restrict__ bsum_d,
        const int* __restrict__ deg_s, int* __restrict__ rp_s, int* __restrict__ bsum_s) {
    int set = blockIdx.x / SCAN_BLKS, blk = blockIdx.x % SCAN_BLKS;
    const int* deg = set ? deg_s : deg_d;
    int* rowptr    = set ? rp_s  : rp_d;
    int* bsum      = set ? bsum_s : bsum_d;
    __shared__ int s[256];
    int tid = threadIdx.x;
    int idx = blk * 256 + tid;
    int v = (idx < N_NODES) ? deg[idx] : 0;
    s[tid] = v; __syncthreads();
    #pragma unroll
    for (int off = 1; off < 256; off <<= 1) {
        int t = (tid >= off) ? s[tid - off] : 0;
        __syncthreads();
        s[tid] += t;
        __syncthreads();
    }
    if (idx < N_NODES) rowptr[idx] = s[tid] - v;   // exclusive
    if (tid == 255) bsum[blk] = s[255];
}

__global__ __launch_bounds__(128) void scan2_both(
        int* __restrict__ bsum_d, int* __restrict__ rp_d,
        int* __restrict__ bsum_s, int* __restrict__ rp_s) {
    int* bsum   = blockIdx.x ? bsum_s : bsum_d;
    int* rowptr = blockIdx.x ? rp_s   : rp_d;
    __shared__ int s[128];
    int tid = threadIdx.x;
    int v = (tid < SCAN_BLKS) ? bsum[tid] : 0;
    s[tid] = v; __syncthreads();
    #pragma unroll
    for (int off = 1; off < 128; off <<= 1) {
        int t = (tid >= off) ? s[tid - off] : 0;
        __syncthreads();
        s[tid] += t;
        __syncthreads();
    }
    if (tid < SCAN_BLKS) bsum[tid] = s[tid] - v;   // exclusive
    if (tid == 0) rowptr[N_NODES] = E_EDGES;
}

__global__ __launch_bounds__(256) void scan3_both(
        int* __restrict__ rp_d, const int* __restrict__ bsum_d, int* __restrict__ cur_d,
        int* __restrict__ rp_s, const int* __restrict__ bsum_s, int* __restrict__ cur_s) {
    int set = blockIdx.x / SCAN_BLKS, blk = blockIdx.x % SCAN_BLKS;
    int* rowptr      = set ? rp_s   : rp_d;
    const int* bsum  = set ? bsum_s : bsum_d;
    int* cursor      = set ? cur_s  : cur_d;
    int idx = blk * 256 + threadIdx.x;
    if (idx < N_NODES) {
        int v = rowptr[idx] + bsum[blk];
        rowptr[idx] = v;
        cursor[idx] = v;
    }
}

// fused scatter: dst-CSR key (src,rel), src-CSR key (rel), and zidx map
__global__ __launch_bounds__(256) void scatter_both(
        const int* __restrict__ ei, const int* __restrict__ et,
        int* __restrict__ cur_d, int* __restrict__ cur_s,
        int* __restrict__ skey, int* __restrict__ skey_s,
        int* __restrict__ zidx) {
    int e = blockIdx.x * 256 + threadIdx.x;
    if (e >= E_EDGES) return;
    int s = ei[e], d = ei[E_EDGES + e], rt = et[e];
    int p = atomicAdd(&cur_d[d], 1);
    skey[p] = (s << 6) | rt;                 // dst-order: (src, rel)
    int qp = atomicAdd(&cur_s[s], 1);
    skey_s[qp] = rt;                         // src-order: rel only
    zidx[p] = qp;                            // dst-slot -> Z row (src-slot)
}

// ---- both layers' basis -> Bt (transposed bf16, zero-padded), one dispatch ----
__global__ __launch_bounds__(256) void split_bt_both(
        const float* __restrict__ basis1, ushort_t* __restrict__ Bt1,
        const float* __restrict__ basis2, ushort_t* __restrict__ Bt2) {
    int idx = blockIdx.x * 256 + threadIdx.x;
    const int n1 = OUTW * KP1;
    if (idx < n1) {
        int n = idx / KP1, k = idx - n * KP1;
        int b = n / HID, o = n - b * HID;
        float v = (k < IN_CH) ? basis1[((size_t)b * IN_CH + k) * HID + o] : 0.f;
        Bt1[idx] = f2bf_rne(v);
    } else {
        int i2 = idx - n1;
        if (i2 >= OUTW * KP2) return;
        int n = i2 / KP2, k = i2 - n * KP2;
        int b = n / HID, o = n - b * HID;
        float v = (k < HID) ? basis2[((size_t)b * HID + k) * HID + o] : 0.f;
        Bt2[i2] = f2bf_rne(v);
    }
}

// ---- A (f32, [M,K]) -> bf16 [MPAD, KP] zero-padded (K tail, M tail) ----
template<int K, int KP, int RELU>
__global__ __launch_bounds__(256) void cvt_pad_bf16(
        const float* __restrict__ in, ushort_t* __restrict__ out, int M) {
    constexpr int CH = KP / 8;
    int idx = blockIdx.x * 256 + threadIdx.x;
    if (idx >= MPAD * CH) return;
    int n = idx / CH, c = idx - n * CH;
    int k = c * 8;
    float v[8];
    if (n < M && k + 8 <= K) {
        float4 f0 = *(const float4*)&in[(size_t)n * K + k];
        float4 f1 = *(const float4*)&in[(size_t)n * K + k + 4];
        v[0]=f0.x; v[1]=f0.y; v[2]=f0.z; v[3]=f0.w;
        v[4]=f1.x; v[5]=f1.y; v[6]=f1.z; v[7]=f1.w;
    } else {
        #pragma unroll
        for (int i = 0; i < 8; i++)
            v[i] = (n < M && k + i < K) ? in[(size_t)n * K + k + i] : 0.f;
    }
    if (RELU) {
        #pragma unroll
        for (int i = 0; i < 8; i++) v[i] = fmaxf(v[i], 0.f);
    }
    ushort8 hv;
    #pragma unroll
    for (int i = 0; i < 8; i++) hv[i] = f2bf_rne(v[i]);
    *(ushort8*)&out[(size_t)n * KP + k] = hv;
}

// ---- MFMA GEMM: xbh[M,800](bf16) = Ab[M,KP](bf16) * B[KP,800] ----
// 480 blocks = 10 col-blocks (80 cols) x 48 row-groups, 512 threads.
// XCD-affine mapping: all 10 col-blocks of one row-group land on the SAME
// XCD (blockIdx % 8 = XCD round-robin), so each XCD fetches its A rows
// from HBM once and the other 9 col-blocks hit that XCD's private L2.
// Per-XCD window: 6 rgs x ~1.7 MB A + 0.5 MB B < 4 MB L2.
// Each block stages its 80 x KP B tile into LDS ONCE (pad stride SW=KP+8),
// one barrier, then a barrier-free row-chunk loop: 8 waves x 32 rows.
template<int KP>
__global__ __launch_bounds__(512, 2) void gemm_mfma(
        const ushort_t* __restrict__ Ab, const ushort_t* __restrict__ Bt,
        ushort_t* __restrict__ xbh, int M) {
    constexpr int KSTEPS = KP / 32;           // 10 (layer1) / 4 (layer2)
    constexpr int SW = KP + 8;                // LDS col stride (ushorts)
    constexpr int CH = KP / 8;
    __shared__ ushort_t Bs[80 * SW];          // 52.5 KB (L1) / 21.3 KB (L2)
    int tid = threadIdx.x, lane = tid & 63, wave = tid >> 6;
    int ml = lane & 15, quad = lane >> 4;
    // XCD-affine de-swizzle: b = (rg&7) + 8*cb + 80*(rg>>3)
    int b = blockIdx.x;
    int xcd = b & 7, qq = b >> 3;
    int cb = qq % 10;                         // 10 col blocks of 80
    int rg = xcd + 8 * (qq / 10);             // 0..47
    int col0 = cb * 80;

    // ---- stage B tile once (coalesced 16B chunks) ----
    for (int t = tid; t < 80 * CH; t += 512) {
        int c = t / CH, ch = t - c * CH;
        *(ushort8*)&Bs[c * SW + ch * 8] =
            *(const ushort8*)&Bt[(size_t)(col0 + c) * KP + ch * 8];
    }
    __syncthreads();                          // the ONLY barrier

    const ushort_t* bb = &Bs[(size_t)ml * SW + quad * 8];

    for (int g = rg; g < NPAIR; g += GEMM_RG) {
        int rbase = g * 256 + wave * 32;      // this wave's 32 rows
        const ushort_t* ar0 = Ab + (size_t)(rbase + ml) * KP + quad * 8;
        const ushort_t* ar1 = ar0 + (size_t)16 * KP;
        short8 a0[KSTEPS], a1[KSTEPS];
        #pragma unroll
        for (int ks = 0; ks < KSTEPS; ks++) {
            a0[ks] = *(const short8*)(ar0 + ks * 32);
            a1[ks] = *(const short8*)(ar1 + ks * 32);
        }
        f32x4 acc0[5] = {}, acc1[5] = {};
        #pragma unroll
        for (int ks = 0; ks < KSTEPS; ks++) {
            short8 bf[5];
            #pragma unroll
            for (int nt = 0; nt < 5; nt++)
                bf[nt] = *(const short8*)(bb + nt * 16 * SW + ks * 32);
            #pragma unroll
            for (int nt = 0; nt < 5; nt++) {
                acc0[nt] = __builtin_amdgcn_mfma_f32_16x16x32_bf16(
                               a0[ks], bf[nt], acc0[nt], 0, 0, 0);
                acc1[nt] = __builtin_amdgcn_mfma_f32_16x16x32_bf16(
                               a1[ks], bf[nt], acc1[nt], 0, 0, 0);
            }
        }
        // epilogue (C layout: row = quad*4 + r, col = nt*16 + ml)
        #pragma unroll
        for (int nt = 0; nt < 5; nt++) {
            #pragma unroll
            for (int r = 0; r < 4; r++) {
                int g0 = rbase + quad * 4 + r;
                if (g0 < M)
                    xbh[(size_t)g0 * OUTW + col0 + nt * 16 + ml] =
                        f2bf_rne(acc0[nt][r]);
                int g1 = g0 + 16;
                if (g1 < M)
                    xbh[(size_t)g1 * OUTW + col0 + nt * 16 + ml] =
                        f2bf_rne(acc1[nt][r]);
            }
        }
    }
}

// ---- xbq[n,b] = xbh[n,b,:].q ; xbk likewise (reads bf16 xbh, coalesced) ----
__global__ __launch_bounds__(256) void qk3_kernel(
        const ushort_t* __restrict__ xbh, const float* __restrict__ q,
        const float* __restrict__ k, float* __restrict__ xbq,
        float* __restrict__ xbk) {
    __shared__ float sq[HID], sk[HID];
    int tid = threadIdx.x;
    if (tid < HID) { sq[tid] = q[tid]; sk[tid] = k[tid]; }
    __syncthreads();
    int idx = blockIdx.x * 256 + tid;     // idx = n*8 + b
    if (idx >= N_NODES * NB) return;
    const ushort_t* xr = xbh + (size_t)(idx >> 3) * OUTW + (idx & 7) * HID;
    float aq = 0.f, ak = 0.f;
    #pragma unroll
    for (int c = 0; c < 25; c++) {        // 25 x ushort4 (8B aligned)
        ushort4 v = *(const ushort4*)&xr[c * 4];
        #pragma unroll
        for (int i = 0; i < 4; i++) {
            float f = bf2f(((const ushort_t*)&v)[i]);
            aq = fmaf(f, sq[c * 4 + i], aq);
            ak = fmaf(f, sk[c * 4 + i], ak);
        }
    }
    xbq[idx] = aq;
    xbk[idx] = ak;
}

// ==== src-major, batched-4 Z rows; comp in LDS; keys via register window ====
// lane = eg*16 + c16; covers channels [8*c16, 8*c16+8) of edge p0+eg.
__global__ __launch_bounds__(256) void compute_z(
        const int* __restrict__ rowptr_s, const int* __restrict__ skey_s,
        const float* __restrict__ comp, const ushort_t* __restrict__ xbh,
        ushort_t* __restrict__ Z) {
    __shared__ float scomp[R_REL * NB];   // 1.6 KB
    int tid = threadIdx.x;
    for (int i = tid; i < R_REL * NB; i += 256) scomp[i] = comp[i];
    __syncthreads();
    int wave = tid >> 6, lane = tid & 63;
    int s = blockIdx.x * 4 + wave;
    if (s >= N_NODES) return;
    int beg = rowptr_s[s], end = rowptr_s[s + 1];
    if (beg == end) return;
    int eg = lane >> 4, c16 = lane & 15;
    int cbase = c16 * 8;
    float xr[NB][8];
    #pragma unroll
    for (int b = 0; b < NB; b++)
        #pragma unroll
        for (int i = 0; i < 8; i++) xr[b][i] = 0.f;
    if (cbase < HID) {
        #pragma unroll
        for (int b = 0; b < NB; b++) {
            const ushort_t* base = xbh + (size_t)s * OUTW + b * HID + cbase;
            ushort4 v0 = *(const ushort4*)base;       // 8B aligned
            xr[b][0] = bf2f(v0.x); xr[b][1] = bf2f(v0.y);
            xr[b][2] = bf2f(v0.z); xr[b][3] = bf2f(v0.w);
            if (cbase + 8 <= HID) {
                ushort4 v1 = *(const ushort4*)(base + 4);
                xr[b][4] = bf2f(v1.x); xr[b][5] = bf2f(v1.y);
                xr[b][6] = bf2f(v1.z); xr[b][7] = bf2f(v1.w);
            }
        }
    }
    for (int w0 = beg; w0 < end; w0 += 64) {
        // one coalesced key load covers the next 64 edges (16 quads)
        int kw = (w0 + lane < end) ? skey_s[w0 + lane] : 0;
        int wend = w0 + 64 < end ? w0 + 64 : end;
        for (int p0 = w0; p0 < wend; p0 += 4) {
            int j = p0 - w0 + eg;              // < 64 always
            int rt = __shfl(kw, j) & 63;       // zero memory ops in chain
            int p = p0 + eg;
            const float* cr = &scomp[rt * NB];
            float z[8] = {};
            #pragma unroll
            for (int b = 0; b < NB; b++) {
                float cb = cr[b];
                #pragma unroll
                for (int i = 0; i < 8; i++) z[i] = fmaf(cb, xr[b][i], z[i]);
            }
            ushort8 zz;
            #pragma unroll
            for (int i = 0; i < 8; i++) zz[i] = f2bf_rne(z[i]);
            if (p < end)
                *(ushort8*)&Z[(size_t)p * ZW + cbase] = zz;   // 16B, coalesced
        }
    }
}

// ==== dst-major: online softmax + paired-edge Z gather + bias; comp in LDS ====
// WB=1: write relu'd bf16 into padded layer-2 A buffer (hb) instead of f32 h
// (identical RNE rounding of the identical f32 value as the old cvt_pad).
template<int WB>
__global__ __launch_bounds__(256) void msg_soft(
        const int* __restrict__ rowptr, const int* __restrict__ skey,
        const int* __restrict__ zidx,
        const float* __restrict__ comp, const ushort_t* __restrict__ Z,
        const float* __restrict__ xbq, const float* __restrict__ xbk,
        const float* __restrict__ bias, float* __restrict__ h,
        ushort_t* __restrict__ hb) {
    __shared__ float scomp[R_REL * NB];   // 1.6 KB
    int tid = threadIdx.x;
    for (int i = tid; i < R_REL * NB; i += 256) scomp[i] = comp[i];
    __syncthreads();
    int wave = tid >> 6, lane = tid & 63;
    int d = blockIdx.x * 4 + wave;
    if (d >= N_NODES) return;
    int beg = rowptr[d], end = rowptr[d + 1];

    float4 qd0 = *(const float4*)&xbq[d * NB];
    float4 qd1 = *(const float4*)&xbq[d * NB + 4];

    int l5 = lane & 31;
    bool act = l5 < 25;
    int oc = l5 * 4;                  // channel base (4 channels per lane)
    f32x4 acc = {0.f, 0.f, 0.f, 0.f};
    float m = -1e30f, l = 0.f;

    for (int c0 = beg; c0 < end; c0 += 64) {
        int p = c0 + lane;
        bool valid = p < end;
        float a = -1e30f;
        int zi = 0;
        if (valid) {
            int key = skey[p];
            zi = zidx[p];
            int s = key >> 6, rt = key & 63;
            const float4 c0v = *(const float4*)&scomp[rt * NB];
            const float4 c1v = *(const float4*)&scomp[rt * NB + 4];
            const float4 k0v = *(const float4*)&xbk[s * NB];
            const float4 k1v = *(const float4*)&xbk[s * NB + 4];
            float qi = c0v.x*qd0.x + c0v.y*qd0.y + c0v.z*qd0.z + c0v.w*qd0.w
                     + c1v.x*qd1.x + c1v.y*qd1.y + c1v.z*qd1.z + c1v.w*qd1.w;
            float kj = c0v.x*k0v.x + c0v.y*k0v.y + c0v.z*k0v.z + c0v.w*k0v.w
                     + c1v.x*k1v.x + c1v.y*k1v.y + c1v.z*k1v.z + c1v.w*k1v.w;
            float av = qi + kj;
            a = av > 0.f ? av : 0.2f * av;  // leaky_relu 0.2
        }
        float cm = a;
        #pragma unroll
        for (int off = 32; off; off >>= 1) cm = fmaxf(cm, __shfl_xor(cm, off));
        float M = fmaxf(m, cm);
        float scale = __expf(m - M);
        acc *= scale; l *= scale; m = M;
        float wgt = valid ? __expf(a - M) : 0.f;
        float cs = wgt;
        #pragma unroll
        for (int off = 32; off; off >>= 1) cs += __shfl_xor(cs, off);
        l += cs;
        int cnt = end - c0; if (cnt > 64) cnt = 64;
        for (int j = 0; j < cnt; j += 2) {
            int jj = j + (lane >> 5);         // even half: j, odd half: j+1
            float wj = __shfl(wgt, jj);       // invalid -> 0
            int   zj = __shfl(zi, jj);
            if (act) {
                ushort4 zz = *(const ushort4*)&Z[(size_t)zj * ZW + oc];
                acc.x = fmaf(wj, bf2f(zz.x), acc.x);
                acc.y = fmaf(wj, bf2f(zz.y), acc.y);
                acc.z = fmaf(wj, bf2f(zz.z), acc.z);
                acc.w = fmaf(wj, bf2f(zz.w), acc.w);
            }
        }
    }
    // combine even/odd-edge halves: lane ℓ (<25) += lane ℓ+32
    #pragma unroll
    for (int i = 0; i < 4; i++) acc[i] += __shfl_xor(acc[i], 32);
    if (lane < 25) {
        float inv = 1.f / (l + 1e-16f);
        float4 r;
        r.x = bias[oc]     + acc.x * inv;
        r.y = bias[oc + 1] + acc.y * inv;
        r.z = bias[oc + 2] + acc.z * inv;
        r.w = bias[oc + 3] + acc.w * inv;
        if (WB) {
            ushort4 o;
            o.x = f2bf_rne(fmaxf(r.x, 0.f));
            o.y = f2bf_rne(fmaxf(r.y, 0.f));
            o.z = f2bf_rne(fmaxf(r.z, 0.f));
            o.w = f2bf_rne(fmaxf(r.w, 0.f));
            *(ushort4*)&hb[(size_t)d * KP2 + oc] = o;   // 8B aligned
        } else {
            *(float4*)&h[(size_t)d * HID + oc] = r;     // 16B aligned
        }
    }
}

// ---- pooled = mean(relu(h2[qidx])); out = pooled @ Wl^T + bl ----
__global__ __launch_bounds__(128) void head_kernel(
        const float* __restrict__ h2, const int* __restrict__ qidx,
        const float* __restrict__ Wl, const float* __restrict__ bl,
        float* __restrict__ out) {
    __shared__ float pooled[HID];
    int tid = threadIdx.x;
    if (tid < HID) {
        float s = 0.f;
        for (int i = 0; i < NQ; i++)
            s += fmaxf(h2[(size_t)qidx[i] * HID + tid], 0.f);
        pooled[tid] = s * (1.0f / NQ);
    }
    __syncthreads();
    if (tid < CLS) {
        float s = bl[tid];
        for (int o = 0; o < HID; o++) s = fmaf(pooled[o], Wl[tid * HID + o], s);
        out[tid] = s;
    }
}

extern "C" void kernel_launch(void* const* d_in, const int* in_sizes, int n_in,
                              void* d_out, int out_size, void* d_ws, size_t ws_size,
                              hipStream_t stream) {
    const float* x      = (const float*)d_in[0];
    const int*   ei     = (const int*)  d_in[1];
    const int*   et     = (const int*)  d_in[2];
    const int*   qidx   = (const int*)  d_in[3];
    const float* comp1  = (const float*)d_in[4];
    const float* basis1 = (const float*)d_in[5];
    const float* q1     = (const float*)d_in[6];
    const float* k1     = (const float*)d_in[7];
    const float* b1     = (const float*)d_in[8];
    const float* comp2  = (const float*)d_in[9];
    const float* basis2 = (const float*)d_in[10];
    const float* q2     = (const float*)d_in[11];
    const float* k2     = (const float*)d_in[12];
    const float* b2     = (const float*)d_in[13];
    const float* Wl     = (const float*)d_in[14];
    const float* bl     = (const float*)d_in[15];
    float* out = (float*)d_out;

    char* w = (char*)d_ws;
    size_t off = 0;
    auto alloc = [&](size_t nbytes) {
        void* p = (void*)(w + off);
        off += ((nbytes + 255) / 256) * 256;
        return p;
    };
    ushort_t* xbh    = (ushort_t*)alloc((size_t)N_NODES * OUTW * 2); // 32 MB
    ushort_t* Z      = (ushort_t*)alloc((size_t)E_EDGES * ZW * 2);   // 82 MB
    float*    h2     = (float*)alloc((size_t)N_NODES * HID * 4);     // 8 MB
    ushort_t* Bt1    = (ushort_t*)alloc((size_t)OUTW * KP1 * 2);     // 512 KB
    ushort_t* Bt2    = (ushort_t*)alloc((size_t)OUTW * KP2 * 2);     // 205 KB
    ushort_t* xbA    = (ushort_t*)alloc((size_t)MPAD * KP1 * 2);     // 12.9 MB
    ushort_t* hbA    = (ushort_t*)alloc((size_t)MPAD * KP2 * 2);     // 5.2 MB
    float*    xbq    = (float*)alloc((size_t)N_NODES * NB * 4);
    float*    xbk    = (float*)alloc((size_t)N_NODES * NB * 4);
    int*      deg_d  = (int*)alloc(N_NODES * 4);
    int*      deg_s  = (int*)alloc(N_NODES * 4);
    int*      rp_d   = (int*)alloc((N_NODES + 1) * 4);
    int*      rp_s   = (int*)alloc((N_NODES + 1) * 4);
    int*      cur_d  = (int*)alloc(N_NODES * 4);
    int*      cur_s  = (int*)alloc(N_NODES * 4);
    int*      bsum_d = (int*)alloc(SCAN_BLKS * 4);
    int*      bsum_s = (int*)alloc(SCAN_BLKS * 4);
    int*      skey   = (int*)alloc(E_EDGES * 4);
    int*      skey_s = (int*)alloc(E_EDGES * 4);
    int*      zidx   = (int*)alloc(E_EDGES * 4);

    // ---- CSR build (once; same graph both layers) + both Bt + A1 upfront ----
    zero_deg2<<<SCAN_BLKS, 256, 0, stream>>>(deg_d, deg_s);
    zero_hbA<<<(MPAD * KP2 / 8 + 255) / 256, 256, 0, stream>>>(hbA);
    hist2_kernel<<<(E_EDGES + 255) / 256, 256, 0, stream>>>(ei, deg_d, deg_s);
    scan1_both<<<2 * SCAN_BLKS, 256, 0, stream>>>(deg_d, rp_d, bsum_d, deg_s, rp_s, bsum_s);
    scan2_both<<<2, 128, 0, stream>>>(bsum_d, rp_d, bsum_s, rp_s);
    scan3_both<<<2 * SCAN_BLKS, 256, 0, stream>>>(rp_d, bsum_d, cur_d, rp_s, bsum_s, cur_s);
    scatter_both<<<(E_EDGES + 255) / 256, 256, 0, stream>>>(ei, et, cur_d, cur_s, skey, skey_s, zidx);
    split_bt_both<<<(OUTW * (KP1 + KP2) + 255) / 256, 256, 0, stream>>>(basis1, Bt1, basis2, Bt2);
    cvt_pad_bf16<IN_CH, KP1, 0><<<(MPAD * (KP1 / 8) + 255) / 256, 256, 0, stream>>>(x, xbA, N_NODES);

    // ---- layer 1 (msg_soft writes relu'd bf16 straight into hbA) ----
    gemm_mfma<KP1><<<10 * GEMM_RG, 512, 0, stream>>>(xbA, Bt1, xbh, N_NODES);
    qk3_kernel<<<(N_NODES * NB + 255) / 256, 256, 0, stream>>>(xbh, q1, k1, xbq, xbk);
    compute_z<<<(N_NODES + 3) / 4, 256, 0, stream>>>(rp_s, skey_s, comp1, xbh, Z);
    msg_soft<1><<<(N_NODES + 3) / 4, 256, 0, stream>>>(rp_d, skey, zidx, comp1, Z, xbq, xbk, b1, (float*)nullptr, hbA);

    // ---- layer 2 ----
    gemm_mfma<KP2><<<10 * GEMM_RG, 512, 0, stream>>>(hbA, Bt2, xbh, N_NODES);
    qk3_kernel<<<(N_NODES * NB + 255) / 256, 256, 0, stream>>>(xbh, q2, k2, xbq, xbk);
    compute_z<<<(N_NODES + 3) / 4, 256, 0, stream>>>(rp_s, skey_s, comp2, xbh, Z);
    msg_soft<0><<<(N_NODES + 3) / 4, 256, 0, stream>>>(rp_d, skey, zidx, comp2, Z, xbq, xbk, b2, h2, (ushort_t*)nullptr);

    head_kernel<<<1, 128, 0, stream>>>(h2, qidx, Wl, bl, out);
}